// Round 13
// baseline (58.780 us; speedup 1.0000x reference)
//
#include <hip/hip_runtime.h>
#include <math.h>

#define N_IN  96
#define N_OUT 192
#define BW    24    // truncated band window width (pass_x / stage A)
#define SP2   104   // Ty row stride in halfs (208B = 13*16B: aligned, bank-spread)

typedef _Float16 h2    __attribute__((ext_vector_type(2)));
typedef _Float16 v8h   __attribute__((ext_vector_type(8)));
typedef float    f32x4 __attribute__((ext_vector_type(4)));

__device__ __forceinline__ unsigned int packh2(float a, float b) {
    h2 h; h.x = (_Float16)a; h.y = (_Float16)b;
    return __builtin_bit_cast(unsigned int, h);
}

__device__ __forceinline__ void fma4(float4& a, float w, const float4& v) {
    a.x += w * v.x; a.y += w * v.y; a.z += w * v.z; a.w += w * v.w;
}

// ---------------- compile-time weight tables ----------------
// M = B_resize(192x96) * A^-1 (A tridiag: diag 2/3, 5/6 at ends, off 1/6),
// constexpr Thomas solve.
//  WB8T/WB4/S8 : banded f32 weights for pass_x and stage A (window BW=24).
//  BF          : DENSE fp16 M^T pre-arranged in mfma_f32_16x16x32_f16 B-frag
//                order: BF[zt][kk][lane][j] = M[zt*16+(lane&15)][kk*32+(lane>>4)*8+j].
struct Tables {
    float          WB8T[24][24][8];
    float          WB4 [48][24][4];
    unsigned short BF  [12][3][64][8];   // 36 KB
    int            S8[24];
};

constexpr int cfold(int idx, int n) {
    int p = 2 * n;
    int m = idx % p; if (m < 0) m += p;
    return (m >= n) ? (p - 1 - m) : m;
}

constexpr unsigned short cph(double v) {
    _Float16 h = (_Float16)(float)v;
    return __builtin_bit_cast(unsigned short, h);
}

constexpr Tables make_tables() {
    Tables T{};
    double cp[N_IN] = {}, minv[N_IN] = {};
    const double a = 1.0 / 6.0;
    minv[0] = 1.0 / (5.0 / 6.0);
    cp[0]   = a * minv[0];
    for (int i = 1; i < N_IN; ++i) {
        double bi = (i == N_IN - 1) ? (5.0 / 6.0) : (2.0 / 3.0);
        minv[i] = 1.0 / (bi - a * cp[i - 1]);
        cp[i]   = a * minv[i];
    }
    for (int j = 0; j < N_OUT; ++j) {
        double x = (double)j * 95.0 / 191.0;
        int    b = (int)x;
        double t = x - (double)b;
        double t2 = t * t, t3 = t2 * t;
        double w0 = (1.0 - t) * (1.0 - t) * (1.0 - t) / 6.0;
        double w1 = (3.0 * t3 - 6.0 * t2 + 4.0) / 6.0;
        double w2 = (-3.0 * t3 + 3.0 * t2 + 3.0 * t + 1.0) / 6.0;
        double w3 = t3 / 6.0;
        double r[N_IN] = {};
        r[cfold(b - 1, N_IN)] += w0;
        r[cfold(b,     N_IN)] += w1;
        r[cfold(b + 1, N_IN)] += w2;
        r[cfold(b + 2, N_IN)] += w3;
        double m[N_IN] = {};
        double dp = 0.0;
        for (int i = 0; i < N_IN; ++i) {
            dp = (i == 0) ? r[0] * minv[0] : (r[i] - a * dp) * minv[i];
            m[i] = dp;
        }
        double xv = 0.0;
        for (int i = N_IN - 1; i >= 0; --i) {
            xv = (i == N_IN - 1) ? m[i] : (m[i] - cp[i] * xv);
            m[i] = xv;
        }
        // dense fp16 M in B-fragment order (stage B, k = z runs over full 96)
        for (int k = 0; k < N_IN; ++k) {
            int kk = k >> 5, hi = (k >> 3) & 3, jj = k & 7;
            T.BF[j >> 4][kk][(hi << 4) | (j & 15)][jj] = cph(m[k]);
        }
        // banded f32 weights (pass_x, stage A)
        int s8 = ((j & ~7) * 95) / 191 - 9;
        if (s8 < 0) s8 = 0; if (s8 > 72) s8 = 72;
        if ((j & 7) == 0) T.S8[j >> 3] = s8;
        for (int tt = 0; tt < BW; ++tt) {
            float mv = (float)m[s8 + tt];
            T.WB8T[j >> 3][tt][j & 7] = mv;
            T.WB4 [j >> 2][tt][j & 3] = mv;
        }
    }
    return T;
}

__device__ const Tables TAB = make_tables();

// ---------------- pass 1: x-expansion ----------------
// in f32 [4][96][9216] -> T1h fp16 [4][192][9216]; blockIdx.y = output oct.
template <int QUADS>
__global__ __launch_bounds__(256)
void pass_x_kernel(const float4* __restrict__ in, uint2* __restrict__ outh) {
    int g  = blockIdx.x * 256 + threadIdx.x;
    int o  = g / QUADS;
    int q  = g - o * QUADS;
    int jo = blockIdx.y;
    int S  = TAB.S8[jo];
    const float4* ip = in + ((size_t)o * N_IN + S) * QUADS + q;
    const float4* wp = (const float4*)(&TAB.WB8T[jo][0][0]);  // wave-uniform
    float4 acc[8];
#pragma unroll
    for (int jj = 0; jj < 8; ++jj) acc[jj] = make_float4(0.f, 0.f, 0.f, 0.f);
#pragma unroll
    for (int t = 0; t < BW; ++t) {
        float4 v   = ip[(size_t)t * QUADS];
        float4 wlo = wp[2 * t];
        float4 whi = wp[2 * t + 1];
        fma4(acc[0], wlo.x, v); fma4(acc[1], wlo.y, v);
        fma4(acc[2], wlo.z, v); fma4(acc[3], wlo.w, v);
        fma4(acc[4], whi.x, v); fma4(acc[5], whi.y, v);
        fma4(acc[6], whi.z, v); fma4(acc[7], whi.w, v);
    }
    uint2* op = outh + ((size_t)o * N_OUT + jo * 8) * QUADS + q;
#pragma unroll
    for (int jj = 0; jj < 8; ++jj) {
        uint2 pk;
        pk.x = packh2(acc[jj].x, acc[jj].y);
        pk.y = packh2(acc[jj].z, acc[jj].w);
        op[(size_t)jj * QUADS] = pk;
    }
}

// ---------------- fused pass 2+3, half blocks ----------------
// Block = (o, h): slab o = (bc,x'), y'-half h -> out[o][h*96+0..95][0..191].
// Stage A (VALU): y-expand 96 rows x 96 z from global into Ty fp16 (banded).
// Stage B (MFMA): out[y'][z'] = sum_z Ty[y'][z] * M[z'][z] via
// mfma_f32_16x16x32_f16; wave w = yt tile (6 waves = 6 yt), 12 zt x 3 kk.
// A-frag = 1 ds_read_b128 from Ty; B-frag = compile-time table, coalesced.
// Plain __launch_bounds__ — min-waves arg spilled to scratch 3x (r6/r7/r9).
__global__ __launch_bounds__(384)
void pass_yz_kernel(const unsigned short* __restrict__ T1h,
                    float* __restrict__ out) {
    __shared__ unsigned short Ty[N_IN * SP2];   // 20 KB
    int bid = blockIdx.x;              // 0..1535
    int o   = bid >> 1;
    int h   = bid & 1;
    int tid = threadIdx.x;             // 0..383

    // ---- Stage A: y-expand rows [h*96, h*96+96), all 96 z-cols, into Ty ----
    for (int task = tid; task < 576; task += 384) {
        int rq = task / 24;            // row-quad 0..23
        int zq = task - rq * 24;       // col-quad 0..23
        int Sg = TAB.S8[(h * 96 + rq * 4) >> 3];
        const float4* wp = (const float4*)(&TAB.WB4[h * 24 + rq][0][0]);
        const unsigned short* sp =
            T1h + (size_t)o * N_IN * N_IN + (size_t)Sg * N_IN + zq * 4;
        float4 a0 = make_float4(0.f,0.f,0.f,0.f), a1 = a0, a2 = a0, a3 = a0;
#pragma unroll
        for (int t = 0; t < BW; ++t) {
            uint2 hv = *(const uint2*)(sp + (size_t)t * N_IN);
            h2 p0 = __builtin_bit_cast(h2, hv.x);
            h2 p1 = __builtin_bit_cast(h2, hv.y);
            float4 v = make_float4((float)p0.x, (float)p0.y,
                                   (float)p1.x, (float)p1.y);
            float4 wq = wp[t];
            fma4(a0, wq.x, v); fma4(a1, wq.y, v);
            fma4(a2, wq.z, v); fma4(a3, wq.w, v);
        }
        unsigned short* ty = Ty + (rq * 4) * SP2 + zq * 4;
        uint2 pk;
        pk.x = packh2(a0.x, a0.y); pk.y = packh2(a0.z, a0.w);
        *(uint2*)(ty + 0 * SP2) = pk;
        pk.x = packh2(a1.x, a1.y); pk.y = packh2(a1.z, a1.w);
        *(uint2*)(ty + 1 * SP2) = pk;
        pk.x = packh2(a2.x, a2.y); pk.y = packh2(a2.z, a2.w);
        *(uint2*)(ty + 2 * SP2) = pk;
        pk.x = packh2(a3.x, a3.y); pk.y = packh2(a3.z, a3.w);
        *(uint2*)(ty + 3 * SP2) = pk;
    }
    __syncthreads();

    // ---- Stage B (MFMA): wave w = yt tile ----
    {
        int w    = tid >> 6;           // 0..5
        int lane = tid & 63;
        // A-frags (one per kk): Ty[w*16 + (lane&15)][kk*32 + (lane>>4)*8 + j]
        const unsigned short* ap = Ty + (w * 16 + (lane & 15)) * SP2
                                   + ((lane >> 4) * 8);
        v8h a0 = __builtin_bit_cast(v8h, *(const uint4*)(ap + 0));
        v8h a1 = __builtin_bit_cast(v8h, *(const uint4*)(ap + 32));
        v8h a2 = __builtin_bit_cast(v8h, *(const uint4*)(ap + 64));
        // B-frag table, 16B per (zt,kk) per lane, coalesced
        const uint4* bf = (const uint4*)(&TAB.BF[0][0][0][0]);
        uint4 nb0 = bf[lane], nb1 = bf[64 + lane], nb2 = bf[128 + lane];
        float* ob = out + (((size_t)o * N_OUT + h * 96 + w * 16
                            + ((lane >> 4) * 4)) * N_OUT) + (lane & 15);
#pragma unroll
        for (int zt = 0; zt < 12; ++zt) {
            uint4 b0 = nb0, b1 = nb1, b2 = nb2;
            if (zt < 11) {
                int base = (zt + 1) * 192 + lane;   // (zt+1)*3*64
                nb0 = bf[base]; nb1 = bf[base + 64]; nb2 = bf[base + 128];
            }
            f32x4 acc = {0.f, 0.f, 0.f, 0.f};
            acc = __builtin_amdgcn_mfma_f32_16x16x32_f16(
                      a0, __builtin_bit_cast(v8h, b0), acc, 0, 0, 0);
            acc = __builtin_amdgcn_mfma_f32_16x16x32_f16(
                      a1, __builtin_bit_cast(v8h, b1), acc, 0, 0, 0);
            acc = __builtin_amdgcn_mfma_f32_16x16x32_f16(
                      a2, __builtin_bit_cast(v8h, b2), acc, 0, 0, 0);
            float* op = ob + zt * 16;
            __builtin_nontemporal_store(acc.x, op + 0 * N_OUT);
            __builtin_nontemporal_store(acc.y, op + 1 * N_OUT);
            __builtin_nontemporal_store(acc.z, op + 2 * N_OUT);
            __builtin_nontemporal_store(acc.w, op + 3 * N_OUT);
        }
    }
}

extern "C" void kernel_launch(void* const* d_in, const int* in_sizes, int n_in,
                              void* d_out, int out_size, void* d_ws, size_t ws_size,
                              hipStream_t stream) {
    const float* in  = (const float*)d_in[0];
    float*       out = (float*)d_out;
    unsigned short* T1h = (unsigned short*)d_ws;  // [4][192][9216] fp16 = 14.2 MB

    // Pass 1: x-axis. in [4][96][2304 f4] -> T1h [4][192][2304 h4]
    {
        dim3 g(4 * 2304 / 256, BW, 1);  // (36, 24)
        pass_x_kernel<2304><<<g, 256, 0, stream>>>((const float4*)in, (uint2*)T1h);
    }
    // Fused pass 2+3: T1h [768 slabs][96][96] -> out [768][192][192]
    pass_yz_kernel<<<768 * 2, 384, 0, stream>>>(T1h, out);
}

// Round 14
// 53.162 us; speedup vs baseline: 1.1057x; 1.1057x over previous
//
#include <hip/hip_runtime.h>
#include <math.h>

#define N_IN  96
#define N_OUT 192
#define BW    24    // truncated band window width (pass_x only)
#define TSP   104   // TzT row stride in halfs (208B = 13*16B: aligned, 2-way max)

typedef _Float16 h2    __attribute__((ext_vector_type(2)));
typedef _Float16 v8h   __attribute__((ext_vector_type(8)));
typedef float    f32x4 __attribute__((ext_vector_type(4)));

__device__ __forceinline__ unsigned int packh2(float a, float b) {
    h2 h; h.x = (_Float16)a; h.y = (_Float16)b;
    return __builtin_bit_cast(unsigned int, h);
}

__device__ __forceinline__ void fma4(float4& a, float w, const float4& v) {
    a.x += w * v.x; a.y += w * v.y; a.z += w * v.z; a.w += w * v.w;
}

__device__ __forceinline__ v8h as8h(const uint4& u) {
    return __builtin_bit_cast(v8h, u);
}

// ---------------- compile-time weight tables ----------------
// M = B_resize(192x96) * A^-1 (A tridiag: diag 2/3, 5/6 at ends, off 1/6),
// constexpr Thomas solve.
//  WB8T/S8 : banded f32 weights for pass_x (window BW=24).
//  BF      : dense fp16 M in mfma_f32_16x16x32_f16 fragment order:
//            BF[t][kk][lane][j] = M[t*16+(lane&15)][kk*32+(lane>>4)*8+j].
//            Serves BOTH as B-frag (z-expansion) and A-frag (y-expansion) —
//            A and B fragments share the same index math. Validated by r13.
struct Tables {
    float          WB8T[24][24][8];
    unsigned short BF  [12][3][64][8];   // 36 KB
    int            S8[24];
};

constexpr int cfold(int idx, int n) {
    int p = 2 * n;
    int m = idx % p; if (m < 0) m += p;
    return (m >= n) ? (p - 1 - m) : m;
}

constexpr unsigned short cph(double v) {
    _Float16 h = (_Float16)(float)v;
    return __builtin_bit_cast(unsigned short, h);
}

constexpr Tables make_tables() {
    Tables T{};
    double cp[N_IN] = {}, minv[N_IN] = {};
    const double a = 1.0 / 6.0;
    minv[0] = 1.0 / (5.0 / 6.0);
    cp[0]   = a * minv[0];
    for (int i = 1; i < N_IN; ++i) {
        double bi = (i == N_IN - 1) ? (5.0 / 6.0) : (2.0 / 3.0);
        minv[i] = 1.0 / (bi - a * cp[i - 1]);
        cp[i]   = a * minv[i];
    }
    for (int j = 0; j < N_OUT; ++j) {
        double x = (double)j * 95.0 / 191.0;
        int    b = (int)x;
        double t = x - (double)b;
        double t2 = t * t, t3 = t2 * t;
        double w0 = (1.0 - t) * (1.0 - t) * (1.0 - t) / 6.0;
        double w1 = (3.0 * t3 - 6.0 * t2 + 4.0) / 6.0;
        double w2 = (-3.0 * t3 + 3.0 * t2 + 3.0 * t + 1.0) / 6.0;
        double w3 = t3 / 6.0;
        double r[N_IN] = {};
        r[cfold(b - 1, N_IN)] += w0;
        r[cfold(b,     N_IN)] += w1;
        r[cfold(b + 1, N_IN)] += w2;
        r[cfold(b + 2, N_IN)] += w3;
        double m[N_IN] = {};
        double dp = 0.0;
        for (int i = 0; i < N_IN; ++i) {
            dp = (i == 0) ? r[0] * minv[0] : (r[i] - a * dp) * minv[i];
            m[i] = dp;
        }
        double xv = 0.0;
        for (int i = N_IN - 1; i >= 0; --i) {
            xv = (i == N_IN - 1) ? m[i] : (m[i] - cp[i] * xv);
            m[i] = xv;
        }
        for (int k = 0; k < N_IN; ++k) {
            int kk = k >> 5, hi = (k >> 3) & 3, jj = k & 7;
            T.BF[j >> 4][kk][(hi << 4) | (j & 15)][jj] = cph(m[k]);
        }
        int s8 = ((j & ~7) * 95) / 191 - 9;
        if (s8 < 0) s8 = 0; if (s8 > 72) s8 = 72;
        if ((j & 7) == 0) T.S8[j >> 3] = s8;
        for (int tt = 0; tt < BW; ++tt)
            T.WB8T[j >> 3][tt][j & 7] = (float)m[s8 + tt];
    }
    return T;
}

__device__ const Tables TAB = make_tables();

// ---------------- pass 1: x-expansion (VALU, banded) ----------------
// in f32 [4][96][9216] -> T1h fp16 [4][192][9216]; blockIdx.y = output oct.
template <int QUADS>
__global__ __launch_bounds__(256)
void pass_x_kernel(const float4* __restrict__ in, uint2* __restrict__ outh) {
    int g  = blockIdx.x * 256 + threadIdx.x;
    int o  = g / QUADS;
    int q  = g - o * QUADS;
    int jo = blockIdx.y;
    int S  = TAB.S8[jo];
    const float4* ip = in + ((size_t)o * N_IN + S) * QUADS + q;
    const float4* wp = (const float4*)(&TAB.WB8T[jo][0][0]);  // wave-uniform
    float4 acc[8];
#pragma unroll
    for (int jj = 0; jj < 8; ++jj) acc[jj] = make_float4(0.f, 0.f, 0.f, 0.f);
#pragma unroll
    for (int t = 0; t < BW; ++t) {
        float4 v   = ip[(size_t)t * QUADS];
        float4 wlo = wp[2 * t];
        float4 whi = wp[2 * t + 1];
        fma4(acc[0], wlo.x, v); fma4(acc[1], wlo.y, v);
        fma4(acc[2], wlo.z, v); fma4(acc[3], wlo.w, v);
        fma4(acc[4], whi.x, v); fma4(acc[5], whi.y, v);
        fma4(acc[6], whi.z, v); fma4(acc[7], whi.w, v);
    }
    uint2* op = outh + ((size_t)o * N_OUT + jo * 8) * QUADS + q;
#pragma unroll
    for (int jj = 0; jj < 8; ++jj) {
        uint2 pk;
        pk.x = packh2(acc[jj].x, acc[jj].y);
        pk.y = packh2(acc[jj].z, acc[jj].w);
        op[(size_t)jj * QUADS] = pk;
    }
}

// ---------------- fused pass 2+3: both expansions on MFMA ----------------
// Block = slab o (768 blocks = 3/CU exactly), 384 threads = 6 waves.
// GEMM-1: Tz[y][z'] = sum_z slab[y][z]*M[z'][z]; A-frag straight from global
//   (slab read once), B = BF table, D packed to LDS TzT[z'][y] (b64 writes).
// GEMM-2: out[y'][z'] = sum_y M[y'][y]*Tz[y][z']; A = BF table, B-frag =
//   ds_read_b128 of TzT rows, D -> global NT dword stores (r13 pattern).
// Plain __launch_bounds__ — min-waves arg spilled to scratch 3x (r6/r7/r9).
__global__ __launch_bounds__(384)
void pass_yz_kernel(const unsigned short* __restrict__ T1h,
                    float* __restrict__ out) {
    __shared__ unsigned short Tz[N_OUT * TSP];   // TzT[z'][y], 39.9 KB
    int o    = blockIdx.x;             // 0..767
    int tid  = threadIdx.x;            // 0..383
    int w    = tid >> 6;               // wave 0..5
    int lane = tid & 63;
    int li   = lane & 15;
    int lg   = lane >> 4;

    const uint4* bf = (const uint4*)(&TAB.BF[0][0][0][0]);

    // ---- GEMM-1: wave w owns y-tile w (rows w*16..w*16+15) ----
    {
        const unsigned short* ap = T1h + (size_t)o * N_IN * N_IN
                                   + (size_t)(w * 16 + li) * N_IN + lg * 8;
        v8h a0 = as8h(*(const uint4*)(ap + 0));
        v8h a1 = as8h(*(const uint4*)(ap + 32));
        v8h a2 = as8h(*(const uint4*)(ap + 64));
        uint4 nb0 = bf[lane], nb1 = bf[64 + lane], nb2 = bf[128 + lane];
#pragma unroll
        for (int zt = 0; zt < 12; ++zt) {
            uint4 b0 = nb0, b1 = nb1, b2 = nb2;
            if (zt < 11) {
                int base = (zt + 1) * 192 + lane;
                nb0 = bf[base]; nb1 = bf[base + 64]; nb2 = bf[base + 128];
            }
            f32x4 acc = {0.f, 0.f, 0.f, 0.f};
            acc = __builtin_amdgcn_mfma_f32_16x16x32_f16(a0, as8h(b0), acc, 0, 0, 0);
            acc = __builtin_amdgcn_mfma_f32_16x16x32_f16(a1, as8h(b1), acc, 0, 0, 0);
            acc = __builtin_amdgcn_mfma_f32_16x16x32_f16(a2, as8h(b2), acc, 0, 0, 0);
            // D[y][z']: col=li -> z' = zt*16+li; rows lg*4+i -> y (4 consec)
            uint2 pk;
            pk.x = packh2(acc.x, acc.y);
            pk.y = packh2(acc.z, acc.w);
            *(uint2*)(Tz + (zt * 16 + li) * TSP + w * 16 + lg * 4) = pk;
        }
    }
    __syncthreads();

    // ---- GEMM-2: wave w owns y'-tiles {w, w+6} ----
    {
        int ytA = w, ytB = w + 6;
        v8h aA0 = as8h(bf[(ytA * 3 + 0) * 64 + lane]);
        v8h aA1 = as8h(bf[(ytA * 3 + 1) * 64 + lane]);
        v8h aA2 = as8h(bf[(ytA * 3 + 2) * 64 + lane]);
        v8h aB0 = as8h(bf[(ytB * 3 + 0) * 64 + lane]);
        v8h aB1 = as8h(bf[(ytB * 3 + 1) * 64 + lane]);
        v8h aB2 = as8h(bf[(ytB * 3 + 2) * 64 + lane]);
        float* obase = out + (size_t)o * N_OUT * N_OUT;
#pragma unroll
        for (int zt = 0; zt < 12; ++zt) {
            const unsigned short* bp = Tz + (zt * 16 + li) * TSP + lg * 8;
            v8h b0 = as8h(*(const uint4*)(bp + 0));
            v8h b1 = as8h(*(const uint4*)(bp + 32));
            v8h b2 = as8h(*(const uint4*)(bp + 64));
            f32x4 accA = {0.f, 0.f, 0.f, 0.f};
            accA = __builtin_amdgcn_mfma_f32_16x16x32_f16(aA0, b0, accA, 0, 0, 0);
            accA = __builtin_amdgcn_mfma_f32_16x16x32_f16(aA1, b1, accA, 0, 0, 0);
            accA = __builtin_amdgcn_mfma_f32_16x16x32_f16(aA2, b2, accA, 0, 0, 0);
            f32x4 accB = {0.f, 0.f, 0.f, 0.f};
            accB = __builtin_amdgcn_mfma_f32_16x16x32_f16(aB0, b0, accB, 0, 0, 0);
            accB = __builtin_amdgcn_mfma_f32_16x16x32_f16(aB1, b1, accB, 0, 0, 0);
            accB = __builtin_amdgcn_mfma_f32_16x16x32_f16(aB2, b2, accB, 0, 0, 0);
            float* opA = obase + (size_t)(ytA * 16 + lg * 4) * N_OUT + zt * 16 + li;
            __builtin_nontemporal_store(accA.x, opA + 0 * N_OUT);
            __builtin_nontemporal_store(accA.y, opA + 1 * N_OUT);
            __builtin_nontemporal_store(accA.z, opA + 2 * N_OUT);
            __builtin_nontemporal_store(accA.w, opA + 3 * N_OUT);
            float* opB = obase + (size_t)(ytB * 16 + lg * 4) * N_OUT + zt * 16 + li;
            __builtin_nontemporal_store(accB.x, opB + 0 * N_OUT);
            __builtin_nontemporal_store(accB.y, opB + 1 * N_OUT);
            __builtin_nontemporal_store(accB.z, opB + 2 * N_OUT);
            __builtin_nontemporal_store(accB.w, opB + 3 * N_OUT);
        }
    }
}

extern "C" void kernel_launch(void* const* d_in, const int* in_sizes, int n_in,
                              void* d_out, int out_size, void* d_ws, size_t ws_size,
                              hipStream_t stream) {
    const float* in  = (const float*)d_in[0];
    float*       out = (float*)d_out;
    unsigned short* T1h = (unsigned short*)d_ws;  // [4][192][9216] fp16 = 14.2 MB

    // Pass 1: x-axis. in [4][96][2304 f4] -> T1h [4][192][2304 h4]
    {
        dim3 g(4 * 2304 / 256, BW, 1);  // (36, 24)
        pass_x_kernel<2304><<<g, 256, 0, stream>>>((const float4*)in, (uint2*)T1h);
    }
    // Fused pass 2+3: T1h [768 slabs][96][96] -> out [768][192][192]
    // one block per slab; both expansions via MFMA
    pass_yz_kernel<<<768, 384, 0, stream>>>(T1h, out);
}

// Round 15
// 50.190 us; speedup vs baseline: 1.1712x; 1.0592x over previous
//
#include <hip/hip_runtime.h>
#include <math.h>

#define N_IN  96
#define N_OUT 192
#define BW    24    // truncated band window width (pass_x only)
#define TSP   104   // TzT row stride in halfs (208B = 13*16B: aligned, 2-way max)

typedef _Float16 h2    __attribute__((ext_vector_type(2)));
typedef _Float16 v8h   __attribute__((ext_vector_type(8)));
typedef float    f32x4 __attribute__((ext_vector_type(4)));

__device__ __forceinline__ unsigned int packh2(float a, float b) {
    h2 h; h.x = (_Float16)a; h.y = (_Float16)b;
    return __builtin_bit_cast(unsigned int, h);
}

__device__ __forceinline__ void fma4(float4& a, float w, const float4& v) {
    a.x += w * v.x; a.y += w * v.y; a.z += w * v.z; a.w += w * v.w;
}

__device__ __forceinline__ v8h as8h(const uint4& u) {
    return __builtin_bit_cast(v8h, u);
}

// ---------------- compile-time weight tables ----------------
// M = B_resize(192x96) * A^-1 (A tridiag: diag 2/3, 5/6 at ends, off 1/6),
// constexpr Thomas solve.
//  WB8T/S8 : banded f32 weights for pass_x (window BW=24).
//  BF      : dense fp16 M in mfma_f32_16x16x32_f16 fragment order:
//            BF[t][kk][lane][j] = M[t*16+(lane&15)][kk*32+(lane>>4)*8+j].
//            Same table serves as A-frag (m=Mrow) or B-frag (n=Mrow) —
//            fragment index math is identical (validated r13/r14).
struct Tables {
    float          WB8T[24][24][8];
    unsigned short BF  [12][3][64][8];   // 36 KB
    int            S8[24];
};

constexpr int cfold(int idx, int n) {
    int p = 2 * n;
    int m = idx % p; if (m < 0) m += p;
    return (m >= n) ? (p - 1 - m) : m;
}

constexpr unsigned short cph(double v) {
    _Float16 h = (_Float16)(float)v;
    return __builtin_bit_cast(unsigned short, h);
}

constexpr Tables make_tables() {
    Tables T{};
    double cp[N_IN] = {}, minv[N_IN] = {};
    const double a = 1.0 / 6.0;
    minv[0] = 1.0 / (5.0 / 6.0);
    cp[0]   = a * minv[0];
    for (int i = 1; i < N_IN; ++i) {
        double bi = (i == N_IN - 1) ? (5.0 / 6.0) : (2.0 / 3.0);
        minv[i] = 1.0 / (bi - a * cp[i - 1]);
        cp[i]   = a * minv[i];
    }
    for (int j = 0; j < N_OUT; ++j) {
        double x = (double)j * 95.0 / 191.0;
        int    b = (int)x;
        double t = x - (double)b;
        double t2 = t * t, t3 = t2 * t;
        double w0 = (1.0 - t) * (1.0 - t) * (1.0 - t) / 6.0;
        double w1 = (3.0 * t3 - 6.0 * t2 + 4.0) / 6.0;
        double w2 = (-3.0 * t3 + 3.0 * t2 + 3.0 * t + 1.0) / 6.0;
        double w3 = t3 / 6.0;
        double r[N_IN] = {};
        r[cfold(b - 1, N_IN)] += w0;
        r[cfold(b,     N_IN)] += w1;
        r[cfold(b + 1, N_IN)] += w2;
        r[cfold(b + 2, N_IN)] += w3;
        double m[N_IN] = {};
        double dp = 0.0;
        for (int i = 0; i < N_IN; ++i) {
            dp = (i == 0) ? r[0] * minv[0] : (r[i] - a * dp) * minv[i];
            m[i] = dp;
        }
        double xv = 0.0;
        for (int i = N_IN - 1; i >= 0; --i) {
            xv = (i == N_IN - 1) ? m[i] : (m[i] - cp[i] * xv);
            m[i] = xv;
        }
        for (int k = 0; k < N_IN; ++k) {
            int kk = k >> 5, hi = (k >> 3) & 3, jj = k & 7;
            T.BF[j >> 4][kk][(hi << 4) | (j & 15)][jj] = cph(m[k]);
        }
        int s8 = ((j & ~7) * 95) / 191 - 9;
        if (s8 < 0) s8 = 0; if (s8 > 72) s8 = 72;
        if ((j & 7) == 0) T.S8[j >> 3] = s8;
        for (int tt = 0; tt < BW; ++tt)
            T.WB8T[j >> 3][tt][j & 7] = (float)m[s8 + tt];
    }
    return T;
}

__device__ const Tables TAB = make_tables();

// ---------------- pass 1: x-expansion (VALU, banded) ----------------
// in f32 [4][96][9216] -> T1h fp16 [4][192][9216]; blockIdx.y = output oct.
template <int QUADS>
__global__ __launch_bounds__(256)
void pass_x_kernel(const float4* __restrict__ in, uint2* __restrict__ outh) {
    int g  = blockIdx.x * 256 + threadIdx.x;
    int o  = g / QUADS;
    int q  = g - o * QUADS;
    int jo = blockIdx.y;
    int S  = TAB.S8[jo];
    const float4* ip = in + ((size_t)o * N_IN + S) * QUADS + q;
    const float4* wp = (const float4*)(&TAB.WB8T[jo][0][0]);  // wave-uniform
    float4 acc[8];
#pragma unroll
    for (int jj = 0; jj < 8; ++jj) acc[jj] = make_float4(0.f, 0.f, 0.f, 0.f);
#pragma unroll
    for (int t = 0; t < BW; ++t) {
        float4 v   = ip[(size_t)t * QUADS];
        float4 wlo = wp[2 * t];
        float4 whi = wp[2 * t + 1];
        fma4(acc[0], wlo.x, v); fma4(acc[1], wlo.y, v);
        fma4(acc[2], wlo.z, v); fma4(acc[3], wlo.w, v);
        fma4(acc[4], whi.x, v); fma4(acc[5], whi.y, v);
        fma4(acc[6], whi.z, v); fma4(acc[7], whi.w, v);
    }
    uint2* op = outh + ((size_t)o * N_OUT + jo * 8) * QUADS + q;
#pragma unroll
    for (int jj = 0; jj < 8; ++jj) {
        uint2 pk;
        pk.x = packh2(acc[jj].x, acc[jj].y);
        pk.y = packh2(acc[jj].z, acc[jj].w);
        op[(size_t)jj * QUADS] = pk;
    }
}

// ---------------- fused pass 2+3: both expansions on MFMA ----------------
// Block = slab o (768 blocks = 3/CU exactly), 384 threads = 6 waves.
// GEMM-1: Tz[y][z'] = sum_z slab[y][z]*M[z'][z]; A-frag straight from global,
//   B = BF table, D packed fp16 to LDS TzT[z'][y] (b64 writes).
// GEMM-2 (TRANSPOSED): D' = TzT * M^T via A-frag = ds_read_b128 TzT rows
//   (m=z', k=y), B-frag = BF[yt] (n=y'). D'[z'][y']: lane = 4 consecutive z'
//   at fixed y' -> ONE f32x4 NT store; a wave's 4 lg-lanes per li fill a full
//   64B line (r14 used 4B dword stores = the store-path bottleneck).
// Plain __launch_bounds__ — min-waves arg spilled to scratch 3x (r6/r7/r9).
__global__ __launch_bounds__(384)
void pass_yz_kernel(const unsigned short* __restrict__ T1h,
                    float* __restrict__ out) {
    __shared__ unsigned short Tz[N_OUT * TSP];   // TzT[z'][y], 39.9 KB
    int o    = blockIdx.x;             // 0..767
    int tid  = threadIdx.x;            // 0..383
    int w    = tid >> 6;               // wave 0..5
    int lane = tid & 63;
    int li   = lane & 15;
    int lg   = lane >> 4;

    const uint4* bf = (const uint4*)(&TAB.BF[0][0][0][0]);

    // ---- GEMM-1: wave w owns y-tile w (rows w*16..w*16+15) ----
    {
        const unsigned short* ap = T1h + (size_t)o * N_IN * N_IN
                                   + (size_t)(w * 16 + li) * N_IN + lg * 8;
        v8h a0 = as8h(*(const uint4*)(ap + 0));
        v8h a1 = as8h(*(const uint4*)(ap + 32));
        v8h a2 = as8h(*(const uint4*)(ap + 64));
        uint4 nb0 = bf[lane], nb1 = bf[64 + lane], nb2 = bf[128 + lane];
#pragma unroll
        for (int zt = 0; zt < 12; ++zt) {
            uint4 b0 = nb0, b1 = nb1, b2 = nb2;
            if (zt < 11) {
                int base = (zt + 1) * 192 + lane;
                nb0 = bf[base]; nb1 = bf[base + 64]; nb2 = bf[base + 128];
            }
            f32x4 acc = {0.f, 0.f, 0.f, 0.f};
            acc = __builtin_amdgcn_mfma_f32_16x16x32_f16(a0, as8h(b0), acc, 0, 0, 0);
            acc = __builtin_amdgcn_mfma_f32_16x16x32_f16(a1, as8h(b1), acc, 0, 0, 0);
            acc = __builtin_amdgcn_mfma_f32_16x16x32_f16(a2, as8h(b2), acc, 0, 0, 0);
            // D[y][z']: col=li -> z' = zt*16+li; rows lg*4+i -> y (4 consec)
            uint2 pk;
            pk.x = packh2(acc.x, acc.y);
            pk.y = packh2(acc.z, acc.w);
            *(uint2*)(Tz + (zt * 16 + li) * TSP + w * 16 + lg * 4) = pk;
        }
    }
    __syncthreads();

    // ---- GEMM-2 (transposed): wave w owns y'-tiles {w, w+6} ----
    {
        int ytA = w, ytB = w + 6;
        v8h bA0 = as8h(bf[(ytA * 3 + 0) * 64 + lane]);
        v8h bA1 = as8h(bf[(ytA * 3 + 1) * 64 + lane]);
        v8h bA2 = as8h(bf[(ytA * 3 + 2) * 64 + lane]);
        v8h bB0 = as8h(bf[(ytB * 3 + 0) * 64 + lane]);
        v8h bB1 = as8h(bf[(ytB * 3 + 1) * 64 + lane]);
        v8h bB2 = as8h(bf[(ytB * 3 + 2) * 64 + lane]);
        float* obase = out + (size_t)o * N_OUT * N_OUT;
#pragma unroll
        for (int zt = 0; zt < 12; ++zt) {
            // A-frag: TzT[zt*16 + li][y = kk*32 + lg*8 + j]
            const unsigned short* ap2 = Tz + (zt * 16 + li) * TSP + lg * 8;
            v8h t0 = as8h(*(const uint4*)(ap2 + 0));
            v8h t1 = as8h(*(const uint4*)(ap2 + 32));
            v8h t2 = as8h(*(const uint4*)(ap2 + 64));
            f32x4 accA = {0.f, 0.f, 0.f, 0.f};
            accA = __builtin_amdgcn_mfma_f32_16x16x32_f16(t0, bA0, accA, 0, 0, 0);
            accA = __builtin_amdgcn_mfma_f32_16x16x32_f16(t1, bA1, accA, 0, 0, 0);
            accA = __builtin_amdgcn_mfma_f32_16x16x32_f16(t2, bA2, accA, 0, 0, 0);
            f32x4 accB = {0.f, 0.f, 0.f, 0.f};
            accB = __builtin_amdgcn_mfma_f32_16x16x32_f16(t0, bB0, accB, 0, 0, 0);
            accB = __builtin_amdgcn_mfma_f32_16x16x32_f16(t1, bB1, accB, 0, 0, 0);
            accB = __builtin_amdgcn_mfma_f32_16x16x32_f16(t2, bB2, accB, 0, 0, 0);
            // D'[z'][y']: col li -> y' = yt*16+li; rows lg*4+i -> z' (consec)
            float* opA = obase + (size_t)(ytA * 16 + li) * N_OUT + zt * 16 + lg * 4;
            __builtin_nontemporal_store(accA, (f32x4*)opA);
            float* opB = obase + (size_t)(ytB * 16 + li) * N_OUT + zt * 16 + lg * 4;
            __builtin_nontemporal_store(accB, (f32x4*)opB);
        }
    }
}

extern "C" void kernel_launch(void* const* d_in, const int* in_sizes, int n_in,
                              void* d_out, int out_size, void* d_ws, size_t ws_size,
                              hipStream_t stream) {
    const float* in  = (const float*)d_in[0];
    float*       out = (float*)d_out;
    unsigned short* T1h = (unsigned short*)d_ws;  // [4][192][9216] fp16 = 14.2 MB

    // Pass 1: x-axis. in [4][96][2304 f4] -> T1h [4][192][2304 h4]
    {
        dim3 g(4 * 2304 / 256, BW, 1);  // (36, 24)
        pass_x_kernel<2304><<<g, 256, 0, stream>>>((const float4*)in, (uint2*)T1h);
    }
    // Fused pass 2+3: T1h [768 slabs][96][96] -> out [768][192][192]
    pass_yz_kernel<<<768, 384, 0, stream>>>(T1h, out);
}